// Round 1
// baseline (167.007 us; speedup 1.0000x reference)
//
#include <hip/hip_runtime.h>
#include <math.h>

// B,H,W,C = 4,384,384,48; KERNEL=3 -> R=Cc=128 outputs per image dim.
// TF-faithful flat view: output F=((b*128+r)*128+cc)*48+g consumes 9
// contiguous floats at row (b*384+3r+kr), offset cc*144+(g&15)*9, kr=g>>4.
// No data reuse across outputs -> LDS staging removed: each lane loads its
// own 36 B directly (2x dwordx4 + dword, all 4B-aligned; a wave's 64 lanes
// cover exactly 2304 contiguous bytes -> every 64B line fully consumed).
#define ROW_STRIDE 18432
#define EPS 1e-4f

static __device__ __forceinline__ float rcp_f(float a) {
    return __builtin_amdgcn_rcpf(a);      // v_rcp_f32, 1 ulp
}

__global__ __launch_bounds__(256) void fuzzy_pool_kernel(
        const float* __restrict__ x, float* __restrict__ out) {
    const int tid = threadIdx.x;
    const int bid = blockIdx.x;           // ((b*128+r)*3 + kr)*8 + c8
    const int c8 = bid & 7;
    const int t1 = bid >> 3;
    const int kr = t1 % 3;                // scalar magic-mul
    const int t2 = t1 / 3;
    const int r  = t2 & 127;
    const int b  = t2 >> 7;

    // thread (i = cc offset 0..15, j = g' 0..15)
    const int i = tid >> 4;
    const int j = tid & 15;

    const float* __restrict__ vp =
        x + ((size_t)(b * 384 + 3 * r + kr) * ROW_STRIDE
             + c8 * 2304 + i * 144 + j * 9);

    // ---- direct global loads: 36 B/lane, 4B-aligned overlapping vectors ----
    float v[9];
    __builtin_memcpy(&v[0], vp, 16);      // floats 0..3  (dwordx4, align 4)
    __builtin_memcpy(&v[4], vp + 4, 16);  // floats 4..7  (dwordx4, align 4)
    v[8] = vp[8];                         // float  8     (dword)

    const float R3 = 1.0f/3.0f, R5 = 0.2f, R7 = 1.0f/7.0f, R9 = 1.0f/9.0f;
    const float NC = -0.5f * 1.44269504088896340736f;   // -0.5*log2(e)

    // ---- membership(x): nested sums ----
    const float s3 = v[3] + v[4] + v[5];
    const float s5 = s3 + v[2] + v[6];
    const float s7 = s5 + v[1] + v[7];
    const float s9 = s7 + v[0] + v[8];
    const float m3 = s3 * R3, m5 = s5 * R5, m7 = s7 * R7, m9 = s9 * R9;

    float kmm[5];
    kmm[0] = m7; kmm[1] = m5; kmm[2] = m3; kmm[3] = v[4]; kmm[4] = m9;

    const float v_avg = (m7 + m5 + m3 + v[4] + m9) * R5;

    // ---- omega = |x - v_avg|; var = membership(omega) + eps ----
    float w[9];
#pragma unroll
    for (int t = 0; t < 9; ++t) w[t] = fabsf(v[t] - v_avg);

    const float t3 = w[3] + w[4] + w[5];
    const float t5 = t3 + w[2] + w[6];
    const float t7 = t5 + w[1] + w[7];
    const float t9 = t7 + w[0] + w[8];
    const float var4 = t9 * R9 + EPS;        // var[...,4] (m_only_var probe)

    float c[5];                               // c_j = -0.5*log2e / var_j
    c[0] = NC * rcp_f(t7 * R7 + EPS);
    c[1] = NC * rcp_f(t5 * R5 + EPS);
    c[2] = NC * rcp_f(t3 * R3 + EPS);
    c[3] = NC * rcp_f(w[4] + EPS);
    c[4] = NC * rcp_f(var4);

    // ---- pi[jj][t] = 2^(c_jj * d^2); sum over jj all t, max over jj t!=4 ----
    // Exact: pi[3][4] = 1.0 bit-exactly; all pi <= 1 so max_pi[4] = 1.0 and
    // t=4 drops out of the thresh min-tree.
    float sum_pi[9], max_pi[9];
#pragma unroll
    for (int t = 0; t < 9; ++t) { sum_pi[t] = 0.f; max_pi[t] = 0.f; }

#pragma unroll
    for (int jj = 0; jj < 5; ++jj) {
        const float k  = kmm[jj];
        const float cj = c[jj];
#pragma unroll
        for (int t = 0; t < 9; ++t) {
            if (jj == 3 && t == 4) {          // d = v[4]-v[4] = +-0 exactly
                sum_pi[4] += 1.0f;            // same summation slot/order
                continue;
            }
            const float d  = v[t] - k;
            const float pi = __builtin_amdgcn_exp2f(cj * d * d); // v_exp_f32
            sum_pi[t] += pi;
            if (t != 4) max_pi[t] = fmaxf(max_pi[t], pi);
        }
    }

    float thresh = fminf(fminf(max_pi[0], max_pi[1]), max_pi[2]);
    thresh = fminf(thresh, max_pi[3]);
    thresh = fminf(fminf(thresh, max_pi[5]), max_pi[6]);
    thresh = fminf(fminf(thresh, max_pi[7]), max_pi[8]);

    // any_t(sum_pi[t]*0.2 > thresh)  <=>  max_t(sum_pi)*0.2 > thresh
    // (x*0.2 rounding is monotone => exact equivalence)
    float ms = fmaxf(fmaxf(sum_pi[0], sum_pi[1]), sum_pi[2]);
    ms = fmaxf(fmaxf(ms, sum_pi[3]), sum_pi[4]);
    ms = fmaxf(fmaxf(ms, sum_pi[5]), sum_pi[6]);
    ms = fmaxf(fmaxf(ms, sum_pi[7]), sum_pi[8]);
    const bool m_mem = (ms * R5) > thresh;

    // weighted-average denoising; the 0.2 factor cancels in the ratio
    float sn = 0.f, sd = 0.f;
#pragma unroll
    for (int t = 0; t < 9; ++t) { sn += sum_pi[t] * v[t]; sd += sum_pi[t]; }
    const float denoised = sn * rcp_f(sd);

    const float res = m_mem ? m9 : ((var4 < EPS) ? v_avg : denoised);

    const int cc = c8 * 16 + i;
    const int g  = kr * 16 + j;
    out[((size_t)((b * 128 + r) * 128 + cc)) * 48 + g] = res;
}

extern "C" void kernel_launch(void* const* d_in, const int* in_sizes, int n_in,
                              void* d_out, int out_size, void* d_ws, size_t ws_size,
                              hipStream_t stream) {
    (void)in_sizes; (void)n_in; (void)d_ws; (void)ws_size; (void)out_size;
    const float* x = (const float*)d_in[0];
    float* out = (float*)d_out;
    const int blocks = 4 * 128 * 3 * 8;   // (b, r, kr, cc-octet) = 12288
    fuzzy_pool_kernel<<<blocks, 256, 0, stream>>>(x, out);
}